// Round 10
// baseline (593.564 us; speedup 1.0000x reference)
//
#include <hip/hip_runtime.h>
#include <hip/hip_bf16.h>

#define T_LEN 1024
#define NT 128

typedef int i32x8 __attribute__((ext_vector_type(8)));
typedef float f32x4 __attribute__((ext_vector_type(4)));

__device__ __forceinline__ unsigned short f2bf(float x) {
  __hip_bfloat16 h = __float2bfloat16(x);  // RNE
  return *reinterpret_cast<unsigned short*>(&h);
}

// ---- prepass: fqh[((blk*1024+t)*4+q)*64 + lane] (ushort8, bf16) =
//      exp(feats[b=blk*16+c][t][32g+8q+e]), lane=(c,g). Coalesced 16B writes.
__global__ __launch_bounds__(256) void crf_prep_kernel(
    const float* __restrict__ feats, unsigned short* __restrict__ fqh) {
  const int n = 8 * 1024 * 4 * 64;  // ushort8 items
  int i = blockIdx.x * 256 + (int)threadIdx.x;
  const int stride = gridDim.x * 256;
  for (; i < n; i += stride) {
    const int lane = i & 63;
    const int q = (i >> 6) & 3;
    const int t = (i >> 8) & 1023;
    const int blk = i >> 18;
    const int c = lane & 15, g = lane >> 4;
    const int b = blk * 16 + c;
    const int row0 = 32 * g + 8 * q;
    const float* src = feats + ((size_t)b * T_LEN + t) * NT + row0;
    float4 v0 = *reinterpret_cast<const float4*>(src);
    float4 v1 = *reinterpret_cast<const float4*>(src + 4);
    ushort ua[8];
    ua[0] = f2bf(__expf(v0.x)); ua[1] = f2bf(__expf(v0.y));
    ua[2] = f2bf(__expf(v0.z)); ua[3] = f2bf(__expf(v0.w));
    ua[4] = f2bf(__expf(v1.x)); ua[5] = f2bf(__expf(v1.y));
    ua[6] = f2bf(__expf(v1.z)); ua[7] = f2bf(__expf(v1.w));
    *reinterpret_cast<uint4*>(fqh + (size_t)i * 8) =
        *reinterpret_cast<uint4*>(ua);
  }
}

// ---- scan: 8 blocks x 1 wave, 16 seqs per wave, registers only.
// E = 1 + D. Per step: u = (SW*1 + D.W)*ef; W=u/Su; K += log Su.
// D.W via 8x mfma_scale_f32_16x16x128_f8f6f4 (A = D*2^5 in e4m3, MX scale
// 2^-5; B = W in e4m3, scale 1). Row map rho(mt,m)=32*(m>>2)+4*mt+(m&3),
// k map 32g+e (A/B-symmetric => matmul invariant; C/D layout is the
// verified 16x16 map). C->B is register renaming: no LDS/barrier/shuffle.
__global__ __launch_bounds__(64, 1) void crf_scan_kernel(
    const unsigned short* __restrict__ fqh, const float* __restrict__ trans,
    const float* __restrict__ start, const float* __restrict__ stop,
    float* __restrict__ fwd_out) {
  const int tid = (int)threadIdx.x;
  const int c = tid & 15;
  const int g = tid >> 4;
  const int blk = blockIdx.x;

  const uint4* fq4 = reinterpret_cast<const uint4*>(fqh);

  // ---- A fragments: Afrag[mt] byte e = e4m3((exp(trans[rb+4mt][32g+e])-1)*32)
  i32x8 Afrag[8];
  const int rbase = 32 * (c >> 2) + (c & 3);
#pragma unroll
  for (int mt = 0; mt < 8; ++mt) {
    const float* tr = trans + (size_t)(rbase + 4 * mt) * NT + 32 * g;
#pragma unroll
    for (int n = 0; n < 8; ++n) {
      float4 t4 = *reinterpret_cast<const float4*>(tr + 4 * n);
      float d0 = (__expf(t4.x) - 1.0f) * 32.0f;
      float d1 = (__expf(t4.y) - 1.0f) * 32.0f;
      float d2 = (__expf(t4.z) - 1.0f) * 32.0f;
      float d3 = (__expf(t4.w) - 1.0f) * 32.0f;
      int lo = __builtin_amdgcn_cvt_pk_fp8_f32(d0, d1, 0, false);
      Afrag[mt][n] = __builtin_amdgcn_cvt_pk_fp8_f32(d2, d3, lo, true);
    }
  }

  // ---- init t=0
  uint4 EF[3][4];
  float eff[32], efr[32], W[32];
#pragma unroll
  for (int q = 0; q < 4; ++q)
    EF[0][q] = fq4[(size_t)((blk * 1024 + 0) * 4 + q) * 64 + tid];
#pragma unroll
  for (int q = 0; q < 4; ++q) {
#pragma unroll
    for (int p = 0; p < 4; ++p) {
      unsigned int u = (&EF[0][q].x)[p];
      eff[8 * q + 2 * p + 0] = __uint_as_float(u << 16);
      eff[8 * q + 2 * p + 1] = __uint_as_float(u & 0xffff0000u);
    }
  }
#pragma unroll
  for (int n = 0; n < 8; ++n) {
    float4 s4 = *reinterpret_cast<const float4*>(start + 32 * g + 4 * n);
    W[4 * n + 0] = __expf(s4.x) * eff[4 * n + 0];
    W[4 * n + 1] = __expf(s4.y) * eff[4 * n + 1];
    W[4 * n + 2] = __expf(s4.z) * eff[4 * n + 2];
    W[4 * n + 3] = __expf(s4.w) * eff[4 * n + 3];
  }
  float mx = W[0];
#pragma unroll
  for (int i = 1; i < 32; ++i) mx = fmaxf(mx, W[i]);
  mx = fmaxf(mx, __shfl_xor(mx, 16));
  mx = fmaxf(mx, __shfl_xor(mx, 32));
  float K = __logf(mx);
  float rm = __builtin_amdgcn_rcpf(mx);
#pragma unroll
  for (int i = 0; i < 32; ++i) W[i] *= rm;

  i32x8 W8;
#pragma unroll
  for (int n = 0; n < 8; ++n) {
    int lo = __builtin_amdgcn_cvt_pk_fp8_f32(W[4 * n], W[4 * n + 1], 0, false);
    W8[n] = __builtin_amdgcn_cvt_pk_fp8_f32(W[4 * n + 2], W[4 * n + 3], lo,
                                            true);
  }
  // preload ef_1 -> slot1, ef_2 -> slot2
#pragma unroll
  for (int q = 0; q < 4; ++q) {
    EF[1][q] = fq4[(size_t)((blk * 1024 + 1) * 4 + q) * 64 + tid];
    EF[2][q] = fq4[(size_t)((blk * 1024 + 2) * 4 + q) * 64 + tid];
  }

  const f32x4 zero4 = {0.f, 0.f, 0.f, 0.f};

#define STEP(T, SU, SL)                                                      \
  {                                                                          \
    f32x4 m[8];                                                              \
    _Pragma("unroll") for (int mt = 0; mt < 8; ++mt) m[mt] =                 \
        __builtin_amdgcn_mfma_scale_f32_16x16x128_f8f6f4(                    \
            Afrag[mt], W8, zero4, 0, 0, 0, 0x7A7A7A7A, 0, 0x7F7F7F7F);       \
    float sg = 0.f;                                                          \
    _Pragma("unroll") for (int i = 0; i < 32; ++i) sg += W[i];               \
    sg += __shfl_xor(sg, 16);                                                \
    sg += __shfl_xor(sg, 32);                                                \
    float r = __builtin_amdgcn_rcpf(sg);                                     \
    K += __logf(sg);                                                         \
    _Pragma("unroll") for (int q = 0; q < 4; ++q) {                          \
      _Pragma("unroll") for (int p = 0; p < 4; ++p) {                        \
        unsigned int u = (&EF[SU][q].x)[p];                                  \
        float elo = __uint_as_float(u << 16);                                \
        float ehi = __uint_as_float(u & 0xffff0000u);                        \
        eff[8 * q + 2 * p + 0] = elo; efr[8 * q + 2 * p + 0] = elo * r;      \
        eff[8 * q + 2 * p + 1] = ehi; efr[8 * q + 2 * p + 1] = ehi * r;      \
      }                                                                      \
    }                                                                        \
    const int t2 = (T) + 2 > 1023 ? 1023 : (T) + 2;                          \
    _Pragma("unroll") for (int q = 0; q < 4; ++q) EF[SL][q] =                \
        fq4[(size_t)((blk * 1024 + t2) * 4 + q) * 64 + tid];                 \
    _Pragma("unroll") for (int mt = 0; mt < 8; ++mt) {                       \
      W[4 * mt + 0] = fmaf(m[mt][0], efr[4 * mt + 0], eff[4 * mt + 0]);      \
      W[4 * mt + 1] = fmaf(m[mt][1], efr[4 * mt + 1], eff[4 * mt + 1]);      \
      W[4 * mt + 2] = fmaf(m[mt][2], efr[4 * mt + 2], eff[4 * mt + 2]);      \
      W[4 * mt + 3] = fmaf(m[mt][3], efr[4 * mt + 3], eff[4 * mt + 3]);      \
    }                                                                        \
    _Pragma("unroll") for (int n = 0; n < 8; ++n) {                          \
      int lo =                                                               \
          __builtin_amdgcn_cvt_pk_fp8_f32(W[4 * n], W[4 * n + 1], 0, false); \
      W8[n] = __builtin_amdgcn_cvt_pk_fp8_f32(W[4 * n + 2], W[4 * n + 3],    \
                                              lo, true);                     \
    }                                                                        \
  }

  // t = 1..1023, 341 x 3 steps; ring slot = t%3
  for (int tb = 1; tb < 1024; tb += 3) {
    STEP(tb + 0, 1, 0)
    STEP(tb + 1, 2, 1)
    STEP(tb + 2, 0, 2)
  }
#undef STEP

  // ---- final: ans = K + log( sum_rows W[row]*exp(stop[row]) )
  float tot = 0.f;
#pragma unroll
  for (int n = 0; n < 8; ++n) {
    float4 s4 = *reinterpret_cast<const float4*>(stop + 32 * g + 4 * n);
    tot += W[4 * n + 0] * __expf(s4.x) + W[4 * n + 1] * __expf(s4.y) +
           W[4 * n + 2] * __expf(s4.z) + W[4 * n + 3] * __expf(s4.w);
  }
  tot += __shfl_xor(tot, 16);
  tot += __shfl_xor(tot, 32);
  if (g == 0) fwd_out[blk * 16 + c] = K + __logf(tot);
}

__global__ __launch_bounds__(256) void crf_gold_kernel(
    const float* __restrict__ feats, const float* __restrict__ trans,
    const float* __restrict__ start, const float* __restrict__ stop,
    const int* __restrict__ tags, const float* __restrict__ fwd,
    float* __restrict__ diff) {
  const int b = blockIdx.x;
  const int tid = (int)threadIdx.x;
  const int lane = tid & 63;
  const int w = tid >> 6;
  const int* tg = tags + b * T_LEN;
  const float* fb = feats + (size_t)b * T_LEN * NT;

  float acc = 0.f;
  for (int s = tid; s < T_LEN; s += 256) {
    int cu = tg[s];
    acc += fb[s * NT + cu];
    if (s > 0) acc += trans[cu * NT + tg[s - 1]];
  }
#pragma unroll
  for (int off = 1; off <= 32; off <<= 1) acc += __shfl_xor(acc, off);
  __shared__ float wr[4];
  if (lane == 0) wr[w] = acc;
  __syncthreads();
  if (tid == 0) {
    float gold = (wr[0] + wr[1]) + (wr[2] + wr[3]) + start[tg[0]] +
                 stop[tg[T_LEN - 1]];
    diff[b] = fwd[b] - gold;
  }
}

__global__ __launch_bounds__(128) void crf_final_kernel(
    const float* __restrict__ diff, float* __restrict__ out) {
  const int tid = (int)threadIdx.x;
  const int lane = tid & 63;
  const int w = tid >> 6;
  float v = diff[tid];
#pragma unroll
  for (int off = 1; off <= 32; off <<= 1) v += __shfl_xor(v, off);
  __shared__ float wr[2];
  if (lane == 0) wr[w] = v;
  __syncthreads();
  if (tid == 0) out[0] = (wr[0] + wr[1]) * (1.0f / 128.0f);
}

extern "C" void kernel_launch(void* const* d_in, const int* in_sizes, int n_in,
                              void* d_out, int out_size, void* d_ws,
                              size_t ws_size, hipStream_t stream) {
  const float* feats = (const float*)d_in[0];
  const float* trans = (const float*)d_in[1];
  const float* start = (const float*)d_in[2];
  const float* stop = (const float*)d_in[3];
  const int* tags = (const int*)d_in[4];
  // d_in[5] = mask: all-true for this problem; ignored.
  float* ws = (float*)d_ws;
  float* fwd = ws;         // 128 floats
  float* diff = ws + 128;  // 128 floats
  unsigned short* fqh = (unsigned short*)(ws + 256);  // 32 MiB bf16 exp(feats)
  float* out = (float*)d_out;

  crf_prep_kernel<<<2048, 256, 0, stream>>>(feats, fqh);
  crf_scan_kernel<<<8, 64, 0, stream>>>(fqh, trans, start, stop, fwd);
  crf_gold_kernel<<<128, 256, 0, stream>>>(feats, trans, start, stop, tags, fwd,
                                           diff);
  crf_final_kernel<<<1, 128, 0, stream>>>(diff, out);
}

// Round 11
// 551.371 us; speedup vs baseline: 1.0765x; 1.0765x over previous
//
#include <hip/hip_runtime.h>
#include <hip/hip_bf16.h>

#define T_LEN 1024
#define NT 128
#define LOG128 4.852030263919617f
#define LN2 0.6931471805599453f

typedef int i32x8 __attribute__((ext_vector_type(8)));
typedef float f32x4 __attribute__((ext_vector_type(4)));

__device__ __forceinline__ unsigned short f2bf(float x) {
  __hip_bfloat16 h = __float2bfloat16(x);  // RNE
  return *reinterpret_cast<unsigned short*>(&h);
}

// ---- prep: one wave per (b,t). Computes ef=exp(feats[b][t][:]), row mean mu,
// writes efn = ef/mu as bf16 in the scan's lane layout, and logmu[b][t].
// Scan-layout u32 index: ((((b>>4)*1024+t)*4+q)*64 + (c+16g))*4 + e/2,
// where row j = 32g+8q+e, c = b&15.
__global__ __launch_bounds__(256) void crf_prep_kernel(
    const float* __restrict__ feats, unsigned int* __restrict__ efn,
    float* __restrict__ logmu) {
  const int tid = (int)threadIdx.x;
  const int l = tid & 63;
  const int wv = blockIdx.x * 4 + (tid >> 6);  // 0 .. 131071
  const int b = wv >> 10;
  const int t = wv & 1023;
  const float* src = feats + ((size_t)b * T_LEN + t) * NT + 2 * l;
  float e0 = __expf(src[0]);
  float e1 = __expf(src[1]);
  float s = e0 + e1;
  s += __shfl_xor(s, 1);  s += __shfl_xor(s, 2);  s += __shfl_xor(s, 4);
  s += __shfl_xor(s, 8);  s += __shfl_xor(s, 16); s += __shfl_xor(s, 32);
  float rs = __builtin_amdgcn_rcpf(s) * 128.0f;  // 1/mu
  unsigned int lo = f2bf(e0 * rs);
  unsigned int hi = f2bf(e1 * rs);
  unsigned int pk = lo | (hi << 16);
  const int q = (l >> 2) & 3, g = l >> 4, c = b & 15;
  const size_t u32i =
      ((size_t)(((b >> 4) * 1024 + t) * 4 + q) * 64 + (c + 16 * g)) * 4 +
      (l & 3);
  efn[u32i] = pk;
  if (l == 0) logmu[b * 1024 + t] = __logf(s) - LOG128;
}

// ---- scan: 8 blocks x 1 wave, 16 seqs per wave, registers only.
// E = 1 + D; u = S + D.W (8x mfma_scale_f32_16x16x128_f8f6f4, A = D*32 fp8
// with const MX scale 2^-5, B = fp8(Wf) scale 2^0). Per step:
//   S = sum(Wf) (tree in MFMA shadow); d = expbits(S)-127; Ke += d (int!);
//   Wf' = (S + m) * efn * 2^-d;  W8' = fp8(Wf').
// No log/rcp/runtime-scale on the chain. v_t = Wf * 2^Ke * prod(mu).
__global__ __launch_bounds__(64, 1) void crf_scan_kernel(
    const unsigned int* __restrict__ efn, const float* __restrict__ logmu,
    const float* __restrict__ trans, const float* __restrict__ start,
    const float* __restrict__ stop, float* __restrict__ fwd_out) {
  const int tid = (int)threadIdx.x;
  const int c = tid & 15;
  const int g = tid >> 4;
  const int blk = blockIdx.x;
  const uint4* fq4 = reinterpret_cast<const uint4*>(efn);

  // A fragments: byte e of word n = e4m3((exp(trans[rb+4mt][32g+4n+e])-1)*32)
  i32x8 Afrag[8];
  const int rbase = 32 * (c >> 2) + (c & 3);
#pragma unroll
  for (int mt = 0; mt < 8; ++mt) {
    const float* tr = trans + (size_t)(rbase + 4 * mt) * NT + 32 * g;
#pragma unroll
    for (int n = 0; n < 8; ++n) {
      float4 t4 = *reinterpret_cast<const float4*>(tr + 4 * n);
      float d0 = (__expf(t4.x) - 1.0f) * 32.0f;
      float d1 = (__expf(t4.y) - 1.0f) * 32.0f;
      float d2 = (__expf(t4.z) - 1.0f) * 32.0f;
      float d3 = (__expf(t4.w) - 1.0f) * 32.0f;
      int lo = __builtin_amdgcn_cvt_pk_fp8_f32(d0, d1, 0, false);
      Afrag[mt][n] = __builtin_amdgcn_cvt_pk_fp8_f32(d2, d3, lo, true);
    }
  }

  // Ksum: sum of logmu over this lane's t-quarter of seq blk*16+c
  float Ksum = 0.f;
  {
    const float* lm = logmu + (size_t)(blk * 16 + c) * 1024 + g * 256;
#pragma unroll 8
    for (int k = 0; k < 64; ++k) {
      float4 v = reinterpret_cast<const float4*>(lm)[k];
      Ksum += (v.x + v.y) + (v.z + v.w);
    }
  }

  uint4 EF[3][4];
  float Wf[32];
  i32x8 W8;
  int Ke = 0;

  // ---- init t=0: Wf = exp(start[row]) * efn_0[row]
#pragma unroll
  for (int q = 0; q < 4; ++q)
    EF[0][q] = fq4[(size_t)((blk * 1024 + 0) * 4 + q) * 64 + tid];
#pragma unroll
  for (int q = 0; q < 4; ++q) {
#pragma unroll
    for (int p = 0; p < 4; ++p) {
      unsigned int u = (&EF[0][q].x)[p];
      const int i = 8 * q + 2 * p;
      Wf[i] = __expf(start[32 * g + i]) * __uint_as_float(u << 16);
      Wf[i + 1] =
          __expf(start[32 * g + i + 1]) * __uint_as_float(u & 0xffff0000u);
    }
  }
#pragma unroll
  for (int n = 0; n < 8; ++n) {
    int lo = __builtin_amdgcn_cvt_pk_fp8_f32(Wf[4 * n], Wf[4 * n + 1], 0, false);
    W8[n] = __builtin_amdgcn_cvt_pk_fp8_f32(Wf[4 * n + 2], Wf[4 * n + 3], lo,
                                            true);
  }
  // ring: slot = t % 3; t=1 -> 1, t=2 -> 2, t=3 -> 0
#pragma unroll
  for (int q = 0; q < 4; ++q) {
    EF[1][q] = fq4[(size_t)((blk * 1024 + 1) * 4 + q) * 64 + tid];
    EF[2][q] = fq4[(size_t)((blk * 1024 + 2) * 4 + q) * 64 + tid];
    EF[0][q] = fq4[(size_t)((blk * 1024 + 3) * 4 + q) * 64 + tid];
  }

  const f32x4 zero4 = {0.f, 0.f, 0.f, 0.f};

#define STEP(T, SL, PF)                                                      \
  {                                                                          \
    f32x4 m[8];                                                              \
    _Pragma("unroll") for (int mt = 0; mt < 8; ++mt) m[mt] =                 \
        __builtin_amdgcn_mfma_scale_f32_16x16x128_f8f6f4(                    \
            Afrag[mt], W8, zero4, 0, 0, 0, 0x7A7A7A7A, 0, 0x7F7F7F7F);       \
    float S;                                                                 \
    {                                                                        \
      float s0 = 0.f, s1 = 0.f, s2 = 0.f, s3 = 0.f;                          \
      _Pragma("unroll") for (int i = 0; i < 8; ++i) {                        \
        s0 += Wf[4 * i + 0]; s1 += Wf[4 * i + 1];                            \
        s2 += Wf[4 * i + 2]; s3 += Wf[4 * i + 3];                            \
      }                                                                      \
      S = (s0 + s1) + (s2 + s3);                                             \
      S += __shfl_xor(S, 16);                                                \
      S += __shfl_xor(S, 32);                                                \
    }                                                                        \
    const unsigned int sbits = __float_as_uint(S);                           \
    const int d = (int)(sbits >> 23) - 127;                                  \
    Ke += d;                                                                 \
    const float scf = __uint_as_float((unsigned int)(127 - d) << 23);        \
    float efs[32];                                                           \
    _Pragma("unroll") for (int q = 0; q < 4; ++q) {                          \
      _Pragma("unroll") for (int p = 0; p < 4; ++p) {                        \
        unsigned int u = (&EF[SL][q].x)[p];                                  \
        efs[8 * q + 2 * p + 0] = __uint_as_float(u << 16) * scf;             \
        efs[8 * q + 2 * p + 1] = __uint_as_float(u & 0xffff0000u) * scf;     \
      }                                                                      \
    }                                                                        \
    _Pragma("unroll") for (int i = 0; i < 32; ++i)                           \
        Wf[i] = (S + m[i >> 2][i & 3]) * efs[i];                             \
    _Pragma("unroll") for (int n = 0; n < 8; ++n) {                          \
      int lo = __builtin_amdgcn_cvt_pk_fp8_f32(Wf[4 * n], Wf[4 * n + 1], 0,  \
                                               false);                      \
      W8[n] = __builtin_amdgcn_cvt_pk_fp8_f32(Wf[4 * n + 2], Wf[4 * n + 3],  \
                                              lo, true);                     \
    }                                                                        \
    if (PF) {                                                                \
      _Pragma("unroll") for (int q = 0; q < 4; ++q) EF[SL][q] =              \
          fq4[(size_t)((blk * 1024 + (T) + 3) * 4 + q) * 64 + tid];          \
    }                                                                        \
  }

  // t = 1..1020 with prefetch (340 iters x 3), then 1021..1023 without
  for (int tb = 1; tb < 1021; tb += 3) {
    STEP(tb + 0, 1, true)
    STEP(tb + 1, 2, true)
    STEP(tb + 2, 0, true)
  }
  STEP(1021, 1, false)
  STEP(1022, 2, false)
  STEP(1023, 0, false)
#undef STEP

  // ---- final: ans = Ke*ln2 + Ksum + log( sum_rows Wf[row]*exp(stop[row]) )
  float tot = 0.f;
#pragma unroll
  for (int n = 0; n < 8; ++n) {
    float4 s4 = *reinterpret_cast<const float4*>(stop + 32 * g + 4 * n);
    tot += Wf[4 * n + 0] * __expf(s4.x) + Wf[4 * n + 1] * __expf(s4.y) +
           Wf[4 * n + 2] * __expf(s4.z) + Wf[4 * n + 3] * __expf(s4.w);
  }
  tot += __shfl_xor(tot, 16);
  tot += __shfl_xor(tot, 32);
  Ksum += __shfl_xor(Ksum, 16);
  Ksum += __shfl_xor(Ksum, 32);
  if (g == 0)
    fwd_out[blk * 16 + c] = (float)Ke * LN2 + Ksum + __logf(tot);
}

__global__ __launch_bounds__(256) void crf_gold_kernel(
    const float* __restrict__ feats, const float* __restrict__ trans,
    const float* __restrict__ start, const float* __restrict__ stop,
    const int* __restrict__ tags, const float* __restrict__ fwd,
    float* __restrict__ diff) {
  const int b = blockIdx.x;
  const int tid = (int)threadIdx.x;
  const int lane = tid & 63;
  const int w = tid >> 6;
  const int* tg = tags + b * T_LEN;
  const float* fb = feats + (size_t)b * T_LEN * NT;

  float acc = 0.f;
  for (int s = tid; s < T_LEN; s += 256) {
    int cu = tg[s];
    acc += fb[s * NT + cu];
    if (s > 0) acc += trans[cu * NT + tg[s - 1]];
  }
#pragma unroll
  for (int off = 1; off <= 32; off <<= 1) acc += __shfl_xor(acc, off);
  __shared__ float wr[4];
  if (lane == 0) wr[w] = acc;
  __syncthreads();
  if (tid == 0) {
    float gold = (wr[0] + wr[1]) + (wr[2] + wr[3]) + start[tg[0]] +
                 stop[tg[T_LEN - 1]];
    diff[b] = fwd[b] - gold;
  }
}

__global__ __launch_bounds__(128) void crf_final_kernel(
    const float* __restrict__ diff, float* __restrict__ out) {
  const int tid = (int)threadIdx.x;
  const int lane = tid & 63;
  const int w = tid >> 6;
  float v = diff[tid];
#pragma unroll
  for (int off = 1; off <= 32; off <<= 1) v += __shfl_xor(v, off);
  __shared__ float wr[2];
  if (lane == 0) wr[w] = v;
  __syncthreads();
  if (tid == 0) out[0] = (wr[0] + wr[1]) * (1.0f / 128.0f);
}

extern "C" void kernel_launch(void* const* d_in, const int* in_sizes, int n_in,
                              void* d_out, int out_size, void* d_ws,
                              size_t ws_size, hipStream_t stream) {
  const float* feats = (const float*)d_in[0];
  const float* trans = (const float*)d_in[1];
  const float* start = (const float*)d_in[2];
  const float* stop = (const float*)d_in[3];
  const int* tags = (const int*)d_in[4];
  // d_in[5] = mask: all-true for this problem; ignored.
  float* ws = (float*)d_ws;
  float* fwd = ws;             // 128 floats
  float* diff = ws + 128;      // 128 floats
  float* logmu = ws + 256;     // 128*1024 floats (512 KiB)
  unsigned int* efn = (unsigned int*)(ws + 256 + 128 * 1024);  // 32 MiB bf16
  float* out = (float*)d_out;

  crf_prep_kernel<<<32768, 256, 0, stream>>>(feats, efn, logmu);
  crf_scan_kernel<<<8, 64, 0, stream>>>(efn, logmu, trans, start, stop, fwd);
  crf_gold_kernel<<<128, 256, 0, stream>>>(feats, trans, start, stop, tags, fwd,
                                           diff);
  crf_final_kernel<<<1, 128, 0, stream>>>(diff, out);
}

// Round 12
// 468.487 us; speedup vs baseline: 1.2670x; 1.1769x over previous
//
#include <hip/hip_runtime.h>
#include <hip/hip_bf16.h>

#define T_LEN 1024
#define NT 128
#define LOG128 4.852030263919617f
#define LN2 0.6931471805599453f

typedef int i32x8 __attribute__((ext_vector_type(8)));
typedef float f32x4 __attribute__((ext_vector_type(4)));
typedef short bf16x8 __attribute__((ext_vector_type(8)));

__device__ __forceinline__ unsigned short f2bf(float x) {
  __hip_bfloat16 h = __float2bfloat16(x);  // RNE
  return *reinterpret_cast<unsigned short*>(&h);
}
__device__ __forceinline__ float bf_lo(unsigned int u) {
  return __uint_as_float(u << 16);
}
__device__ __forceinline__ float bf_hi(unsigned int u) {
  return __uint_as_float(u & 0xffff0000u);
}

// ---- prep: efn[(b*1024+t)*64 + l] (u32 = 2 bf16) = exp(feats[b][t][2l..2l+1])/mu,
//      logmu[b][t] = log(mean_j exp(feats[b][t][j])). One wave per (b,t).
__global__ __launch_bounds__(256) void crf_prep_kernel(
    const float* __restrict__ feats, unsigned int* __restrict__ efn,
    float* __restrict__ logmu) {
  const int tid = (int)threadIdx.x;
  const int l = tid & 63;
  const int wv = blockIdx.x * 4 + (tid >> 6);
  const int b = wv >> 10;
  const int t = wv & 1023;
  const float* src = feats + ((size_t)b * T_LEN + t) * NT + 2 * l;
  float e0 = __expf(src[0]);
  float e1 = __expf(src[1]);
  float s = e0 + e1;
  s += __shfl_xor(s, 1);  s += __shfl_xor(s, 2);  s += __shfl_xor(s, 4);
  s += __shfl_xor(s, 8);  s += __shfl_xor(s, 16); s += __shfl_xor(s, 32);
  float rs = __builtin_amdgcn_rcpf(s) * 128.0f;  // 1/mu
  unsigned int pk = (unsigned int)f2bf(e0 * rs) |
                    ((unsigned int)f2bf(e1 * rs) << 16);
  efn[(size_t)(b * 1024 + t) * 64 + l] = pk;
  if (l == 0) logmu[b * 1024 + t] = __logf(s) - LOG128;
}

// ---- phase A: 4096 waves. Wave = (seq, seg, slab): evolves 16 basis
// columns j = 16*slab + c of segment seg's transfer matrix, using R11's
// verified fp8 step (E = 1 + D; u = Sq + D.W; Sq from a 9th all-ones MFMA;
// power-of-2 renorm tracked in integer Ke per column). Registers only.
// Stores T-hat (bf16, true [row][col]) and Ke per column.
__global__ __launch_bounds__(64, 1) void crf_segA_kernel(
    const unsigned int* __restrict__ efn, const float* __restrict__ trans,
    unsigned short* __restrict__ That, int* __restrict__ KeArr) {
  const int tid = (int)threadIdx.x;
  const int c = tid & 15;
  const int g = tid >> 4;
  const int bid = (int)blockIdx.x;
  const int seq = bid >> 5;
  const int seg = (bid >> 3) & 3;
  const int slab = bid & 7;

  // A fragments (R11-verified): byte b of word n =
  // e4m3((exp(trans[rbase+4mt][32g+4n+b]) - 1) * 32), MX scale 2^-5.
  i32x8 Afrag[8];
  const int rbase = 32 * (c >> 2) + (c & 3);
#pragma unroll
  for (int mt = 0; mt < 8; ++mt) {
    const float* tr = trans + (size_t)(rbase + 4 * mt) * NT + 32 * g;
#pragma unroll
    for (int n = 0; n < 8; ++n) {
      float4 t4 = *reinterpret_cast<const float4*>(tr + 4 * n);
      float d0 = (__expf(t4.x) - 1.0f) * 32.0f;
      float d1 = (__expf(t4.y) - 1.0f) * 32.0f;
      float d2 = (__expf(t4.z) - 1.0f) * 32.0f;
      float d3 = (__expf(t4.w) - 1.0f) * 32.0f;
      int lo = __builtin_amdgcn_cvt_pk_fp8_f32(d0, d1, 0, false);
      Afrag[mt][n] = __builtin_amdgcn_cvt_pk_fp8_f32(d2, d3, lo, true);
    }
  }
  i32x8 Aones;
#pragma unroll
  for (int n = 0; n < 8; ++n) Aones[n] = 0x38383838;  // fp8 e4m3 1.0 bytes

  const int t0 = seg * 256;
  const int t1 = (seg == 3) ? 1023 : (t0 + 256);
  const int steps = t1 - t0;

  // ef stream: uint4 index (t*16 + q) from per-seq, per-g base
  const uint4* efq =
      reinterpret_cast<const uint4*>(efn) + (size_t)seq * 1024 * 16 + 4 * g;

  // ---- basis init: Wf[i] = (32g+i == 16*slab+c)
  float Wf[32];
  const int jcol = 16 * slab + c;
#pragma unroll
  for (int i = 0; i < 32; ++i) Wf[i] = (32 * g + i == jcol) ? 1.0f : 0.0f;
  i32x8 W8;
#pragma unroll
  for (int n = 0; n < 8; ++n) {
    int lo = __builtin_amdgcn_cvt_pk_fp8_f32(Wf[4 * n], Wf[4 * n + 1], 0, false);
    W8[n] = __builtin_amdgcn_cvt_pk_fp8_f32(Wf[4 * n + 2], Wf[4 * n + 3], lo,
                                            true);
  }
  int Ke = 0;
  uint4 EF[2][4];
#pragma unroll
  for (int q = 0; q < 4; ++q) {
    EF[0][q] = efq[(size_t)(t0 + 1) * 16 + q];
    EF[1][q] = efq[(size_t)(t0 + 2) * 16 + q];
  }

  const f32x4 zero4 = {0.f, 0.f, 0.f, 0.f};

#define ASTEP(BUF, TT)                                                       \
  {                                                                          \
    f32x4 s4 = __builtin_amdgcn_mfma_scale_f32_16x16x128_f8f6f4(             \
        Aones, W8, zero4, 0, 0, 0, 0x7F7F7F7F, 0, 0x7F7F7F7F);               \
    f32x4 mm[8];                                                             \
    _Pragma("unroll") for (int mt = 0; mt < 8; ++mt) mm[mt] =                \
        __builtin_amdgcn_mfma_scale_f32_16x16x128_f8f6f4(                    \
            Afrag[mt], W8, zero4, 0, 0, 0, 0x7A7A7A7A, 0, 0x7F7F7F7F);       \
    const float Sq = s4[0];                                                  \
    const unsigned int eb = __float_as_uint(Sq) >> 23;                       \
    Ke += (int)eb - 127;                                                     \
    const float scf = __uint_as_float((254u - eb) << 23);                    \
    _Pragma("unroll") for (int q = 0; q < 4; ++q) {                          \
      _Pragma("unroll") for (int p = 0; p < 4; ++p) {                        \
        const unsigned int u = (&EF[BUF][q].x)[p];                           \
        const int i = 8 * q + 2 * p;                                         \
        Wf[i] = (Sq + mm[i >> 2][i & 3]) * (bf_lo(u) * scf);                 \
        Wf[i + 1] = (Sq + mm[(i + 1) >> 2][(i + 1) & 3]) *                   \
                    (bf_hi(u) * scf);                                        \
      }                                                                      \
    }                                                                        \
    const int tp = ((TT) + 2 > t1) ? t1 : ((TT) + 2);                        \
    _Pragma("unroll") for (int q = 0; q < 4; ++q) EF[BUF][q] =               \
        efq[(size_t)tp * 16 + q];                                            \
    _Pragma("unroll") for (int n = 0; n < 8; ++n) {                          \
      int lo = __builtin_amdgcn_cvt_pk_fp8_f32(Wf[4 * n], Wf[4 * n + 1], 0,  \
                                               false);                       \
      W8[n] = __builtin_amdgcn_cvt_pk_fp8_f32(Wf[4 * n + 2], Wf[4 * n + 3],  \
                                              lo, true);                     \
    }                                                                        \
  }

  const int pairs = steps >> 1;
  for (int p = 0; p < pairs; ++p) {
    const int t = t0 + 2 * p + 1;
    ASTEP(0, t)
    ASTEP(1, t + 1)
  }
  if (steps & 1) ASTEP(0, t1)
#undef ASTEP

  // ---- store T-hat[seg][seq][row][col] (bf16) and Ke[seg][seq][col]
  unsigned short* Tb = That + (size_t)(seg * 128 + seq) * 16384;
#pragma unroll
  for (int i = 0; i < 32; ++i)
    Tb[(32 * g + i) * 128 + jcol] = f2bf(Wf[i]);
  if (g == 0) KeArr[(seg * 128 + seq) * 128 + jcol] = Ke;
}

// ---- phase B: one wave per seq. v_0 = exp(start)*efn_0; then 4 matvecs
// v <- T-hat_s * (v .* 2^(Ke_s - KeRef)), bf16 MFMA (R7-verified replicated-
// column pattern), power-of-2 renorm; ans = Ksum + Keacc*ln2 + log(v.stop).
__global__ __launch_bounds__(64, 1) void crf_segB_kernel(
    const unsigned int* __restrict__ efn,
    const unsigned short* __restrict__ That, const int* __restrict__ KeArr,
    const float* __restrict__ logmu, const float* __restrict__ start,
    const float* __restrict__ stop, float* __restrict__ fwd_out) {
  const int tid = (int)threadIdx.x;
  const int c = tid & 15;
  const int g = tid >> 4;
  const int seq = (int)blockIdx.x;

  // Ksum = sum_t logmu[seq][t]
  float Ksum = 0.f;
  {
    const float4* lm =
        reinterpret_cast<const float4*>(logmu + (size_t)seq * 1024) + tid * 4;
#pragma unroll
    for (int k = 0; k < 4; ++k) {
      float4 v4 = lm[k];
      Ksum += (v4.x + v4.y) + (v4.z + v4.w);
    }
    Ksum += __shfl_xor(Ksum, 1);  Ksum += __shfl_xor(Ksum, 2);
    Ksum += __shfl_xor(Ksum, 4);  Ksum += __shfl_xor(Ksum, 8);
    Ksum += __shfl_xor(Ksum, 16); Ksum += __shfl_xor(Ksum, 32);
  }

  // v init from efn_0 and start
  float v[32];
  {
    const uint4* e0 =
        reinterpret_cast<const uint4*>(efn) + (size_t)seq * 1024 * 16 + 4 * g;
#pragma unroll
    for (int q = 0; q < 4; ++q) {
      uint4 u4 = e0[q];
#pragma unroll
      for (int p = 0; p < 4; ++p) {
        const unsigned int u = (&u4.x)[p];
        const int i = 8 * q + 2 * p;
        v[i] = __expf(start[32 * g + i]) * bf_lo(u);
        v[i + 1] = __expf(start[32 * g + i + 1]) * bf_hi(u);
      }
    }
  }
  int Keacc = 0;

#define RENORM                                                        \
  {                                                                   \
    float S = 0.f;                                                    \
    _Pragma("unroll") for (int i = 0; i < 32; ++i) S += v[i];         \
    S += __shfl_xor(S, 16);                                           \
    S += __shfl_xor(S, 32);                                           \
    const unsigned int eb = __float_as_uint(S) >> 23;                 \
    Keacc += (int)eb - 127;                                           \
    const float scf = __uint_as_float((254u - eb) << 23);             \
    _Pragma("unroll") for (int i = 0; i < 32; ++i) v[i] *= scf;       \
  }

  RENORM
  const int rbase = 32 * (c >> 2) + (c & 3);
  const f32x4 zero4 = {0.f, 0.f, 0.f, 0.f};

  for (int s = 0; s < 4; ++s) {
    const unsigned short* Tb = That + (size_t)(s * 128 + seq) * 16384;
    const int* Kb = KeArr + (s * 128 + seq) * 128;
    const int KeRef = Kb[0];
    int4 KL[8];
#pragma unroll
    for (int m = 0; m < 8; ++m)
      KL[m] = reinterpret_cast<const int4*>(Kb + 32 * g)[m];
    bf16x8 ub[4];
#pragma unroll
    for (int kt = 0; kt < 4; ++kt) {
      bf16x8 t;
#pragma unroll
      for (int e = 0; e < 8; ++e) {
        const int i = 8 * kt + e;
        t[e] = (short)f2bf(ldexpf(v[i], (&KL[i >> 2].x)[i & 3] - KeRef));
      }
      ub[kt] = t;
    }
    Keacc += KeRef;
    f32x4 acc[8];
#pragma unroll
    for (int mt = 0; mt < 8; ++mt) acc[mt] = zero4;
#pragma unroll
    for (int kt = 0; kt < 4; ++kt) {
#pragma unroll
      for (int mt = 0; mt < 8; ++mt) {
        bf16x8 a = *reinterpret_cast<const bf16x8*>(
            Tb + (size_t)(rbase + 4 * mt) * 128 + 32 * g + 8 * kt);
        acc[mt] = __builtin_amdgcn_mfma_f32_16x16x32_bf16(a, ub[kt], acc[mt],
                                                          0, 0, 0);
      }
    }
#pragma unroll
    for (int mt = 0; mt < 8; ++mt) {
#pragma unroll
      for (int r = 0; r < 4; ++r) v[4 * mt + r] = acc[mt][r];
    }
    RENORM
  }
#undef RENORM

  float tot = 0.f;
#pragma unroll
  for (int i = 0; i < 32; ++i) tot += v[i] * __expf(stop[32 * g + i]);
  tot += __shfl_xor(tot, 16);
  tot += __shfl_xor(tot, 32);
  if (tid == 0)
    fwd_out[seq] = Ksum + (float)Keacc * LN2 + __logf(tot);
}

__global__ __launch_bounds__(256) void crf_gold_kernel(
    const float* __restrict__ feats, const float* __restrict__ trans,
    const float* __restrict__ start, const float* __restrict__ stop,
    const int* __restrict__ tags, const float* __restrict__ fwd,
    float* __restrict__ diff) {
  const int b = blockIdx.x;
  const int tid = (int)threadIdx.x;
  const int lane = tid & 63;
  const int w = tid >> 6;
  const int* tg = tags + b * T_LEN;
  const float* fb = feats + (size_t)b * T_LEN * NT;

  float acc = 0.f;
  for (int s = tid; s < T_LEN; s += 256) {
    int cu = tg[s];
    acc += fb[s * NT + cu];
    if (s > 0) acc += trans[cu * NT + tg[s - 1]];
  }
#pragma unroll
  for (int off = 1; off <= 32; off <<= 1) acc += __shfl_xor(acc, off);
  __shared__ float wr[4];
  if (lane == 0) wr[w] = acc;
  __syncthreads();
  if (tid == 0) {
    float gold = (wr[0] + wr[1]) + (wr[2] + wr[3]) + start[tg[0]] +
                 stop[tg[T_LEN - 1]];
    diff[b] = fwd[b] - gold;
  }
}

__global__ __launch_bounds__(128) void crf_final_kernel(
    const float* __restrict__ diff, float* __restrict__ out) {
  const int tid = (int)threadIdx.x;
  const int lane = tid & 63;
  const int w = tid >> 6;
  float v = diff[tid];
#pragma unroll
  for (int off = 1; off <= 32; off <<= 1) v += __shfl_xor(v, off);
  __shared__ float wr[2];
  if (lane == 0) wr[w] = v;
  __syncthreads();
  if (tid == 0) out[0] = (wr[0] + wr[1]) * (1.0f / 128.0f);
}

extern "C" void kernel_launch(void* const* d_in, const int* in_sizes, int n_in,
                              void* d_out, int out_size, void* d_ws,
                              size_t ws_size, hipStream_t stream) {
  const float* feats = (const float*)d_in[0];
  const float* trans = (const float*)d_in[1];
  const float* start = (const float*)d_in[2];
  const float* stop = (const float*)d_in[3];
  const int* tags = (const int*)d_in[4];
  // d_in[5] = mask: all-true for this problem; ignored.
  float* ws = (float*)d_ws;
  float* fwd = ws;                       // 128 floats
  float* diff = ws + 128;                // 128 floats
  float* logmu = ws + 256;               // 128*1024 floats
  unsigned int* efn = (unsigned int*)(ws + 256 + 131072);  // 32 MiB
  unsigned short* That =
      (unsigned short*)(efn + (size_t)128 * 1024 * 64);    // 16 MiB bf16
  int* KeArr = (int*)(That + (size_t)512 * 16384);         // 256 KiB
  float* out = (float*)d_out;

  crf_prep_kernel<<<32768, 256, 0, stream>>>(feats, efn, logmu);
  crf_segA_kernel<<<4096, 64, 0, stream>>>(efn, trans, That, KeArr);
  crf_segB_kernel<<<128, 64, 0, stream>>>(efn, That, KeArr, logmu, start, stop,
                                          fwd);
  crf_gold_kernel<<<128, 256, 0, stream>>>(feats, trans, start, stop, tags, fwd,
                                           diff);
  crf_final_kernel<<<1, 128, 0, stream>>>(diff, out);
}